// Round 1
// 216.855 us; speedup vs baseline: 1.0067x; 1.0067x over previous
//
#include <hip/hip_runtime.h>

// Problem constants (from reference): B=8, C=3, H=512, W=512
constexpr int Cc = 3;
constexpr int Hc = 512;
constexpr int Wc = 512;
constexpr int HW = Hc * Wc;            // 262144 = 2^18
constexpr int NPIX = 8 * HW;           // 2097152
constexpr int NGRP = NPIX / 4;         // 524288 groups of 4 consecutive pixels
constexpr int TPB  = 256;
constexpr int NBLK = 1024;             // each thread handles 2 groups (8 pixels)
constexpr int TOT  = NBLK * TPB;       // 262144 threads; groups g = t and t + TOT

// ws layout: [0, NBLK) doubles = per-block partial sums
//            then NBLK floats = per-block partial maxes

// Per-group compute: bit-identical math to the verified baseline.
// sf[] / T*v[] have only compile-time-constant indices after unroll -> SROA to regs.
#define GRP_ACCUM(D0, D1, D2, S0, S1, S2, S3, S4, S5, S6, S7, S8)          \
  do {                                                                     \
    const float sf[36] = {                                                 \
      S0.x,S0.y,S0.z,S0.w, S1.x,S1.y,S1.z,S1.w, S2.x,S2.y,S2.z,S2.w,      \
      S3.x,S3.y,S3.z,S3.w, S4.x,S4.y,S4.z,S4.w, S5.x,S5.y,S5.z,S5.w,      \
      S6.x,S6.y,S6.z,S6.w, S7.x,S7.y,S7.z,S7.w, S8.x,S8.y,S8.z,S8.w };    \
    const float T0v[4] = {D0.x, D0.y, D0.z, D0.w};                         \
    const float T1v[4] = {D1.x, D1.y, D1.z, D1.w};                         \
    const float T2v[4] = {D2.x, D2.y, D2.z, D2.w};                         \
    _Pragma("unroll")                                                      \
    for (int i = 0; i < 4; ++i) {                                          \
      const float* s = sf + i * 9;                                         \
      float s00 = s[0], s01 = s[1], s02 = s[2];                            \
      float s11 = s[4], s12 = s[5], s22 = s[8];                            \
      float a00 = s11 * s22 - s12 * s12;                                   \
      float a01 = s02 * s12 - s01 * s22;                                   \
      float a02 = s01 * s12 - s02 * s11;                                   \
      float a11 = s00 * s22 - s02 * s02;                                   \
      float a12 = s01 * s02 - s00 * s12;                                   \
      float a22 = s00 * s11 - s01 * s01;                                   \
      float det = s00 * a00 + s01 * a01 + s02 * a02;                       \
      float t0 = T0v[i], t1 = T1v[i], t2 = T2v[i];                         \
      float quad = t0 * t0 * a00 + t1 * t1 * a11 + t2 * t2 * a22           \
                 + 2.0f * (t0 * t1 * a01 + t0 * t2 * a02 + t1 * t2 * a12); \
      float t1term = 0.5f * quad / det;                                    \
      float t2term = 0.5f * logf(det);                                     \
      local_sum += (double)(t1term + t2term);                              \
      local_max = fmaxf(local_max, t1term);                                \
    }                                                                      \
  } while (0)

__global__ __launch_bounds__(256, 4) void map_loss_main(
    const float* __restrict__ target,
    const float* __restrict__ mu,
    const float* __restrict__ sigma_y,
    double* __restrict__ part_sum,
    float* __restrict__ part_max)
{
    double local_sum = 0.0;
    float local_max = 0.0f;

    const int t = blockIdx.x * TPB + threadIdx.x;

    // group A = t, group B = t + TOT; both per-instruction coalesced across lanes
    const long long pA = (long long)t << 2;             // first pixel of group A
    const long long pB = (long long)(t + TOT) << 2;     // first pixel of group B
    const int bA = (int)(pA >> 18), bB = (int)(pB >> 18);
    const int hwA = (int)pA & (HW - 1), hwB = (int)pB & (HW - 1);
    const long long baseA = (long long)bA * (Cc * HW) + hwA;
    const long long baseB = (long long)bB * (Cc * HW) + hwB;

    const float4* tgA = (const float4*)(target + baseA);
    const float4* muA = (const float4*)(mu + baseA);
    const float4* tgB = (const float4*)(target + baseB);
    const float4* muB = (const float4*)(mu + baseB);
    const float4* syA = (const float4*)(sigma_y + pA * 9);  // 36*g -> 16B aligned
    const float4* syB = (const float4*)(sigma_y + pB * 9);

    // ---- issue ALL 30 global loads before any consumption (MLP) ----
    float4 At0 = tgA[0];          float4 Am0 = muA[0];
    float4 At1 = tgA[HW / 4];     float4 Am1 = muA[HW / 4];
    float4 At2 = tgA[HW / 2];     float4 Am2 = muA[HW / 2];
    float4 Bt0 = tgB[0];          float4 Bm0 = muB[0];
    float4 Bt1 = tgB[HW / 4];     float4 Bm1 = muB[HW / 4];
    float4 Bt2 = tgB[HW / 2];     float4 Bm2 = muB[HW / 2];

    float4 AS0 = syA[0], AS1 = syA[1], AS2 = syA[2], AS3 = syA[3], AS4 = syA[4];
    float4 AS5 = syA[5], AS6 = syA[6], AS7 = syA[7], AS8 = syA[8];
    float4 BS0 = syB[0], BS1 = syB[1], BS2 = syB[2], BS3 = syB[3], BS4 = syB[4];
    float4 BS5 = syB[5], BS6 = syB[6], BS7 = syB[7], BS8 = syB[8];

    // residuals (frees mu registers as soon as target/mu arrive)
    At0.x -= Am0.x; At0.y -= Am0.y; At0.z -= Am0.z; At0.w -= Am0.w;
    At1.x -= Am1.x; At1.y -= Am1.y; At1.z -= Am1.z; At1.w -= Am1.w;
    At2.x -= Am2.x; At2.y -= Am2.y; At2.z -= Am2.z; At2.w -= Am2.w;
    Bt0.x -= Bm0.x; Bt0.y -= Bm0.y; Bt0.z -= Bm0.z; Bt0.w -= Bm0.w;
    Bt1.x -= Bm1.x; Bt1.y -= Bm1.y; Bt1.z -= Bm1.z; Bt1.w -= Bm1.w;
    Bt2.x -= Bm2.x; Bt2.y -= Bm2.y; Bt2.z -= Bm2.z; Bt2.w -= Bm2.w;

    GRP_ACCUM(At0, At1, At2, AS0, AS1, AS2, AS3, AS4, AS5, AS6, AS7, AS8);
    GRP_ACCUM(Bt0, Bt1, Bt2, BS0, BS1, BS2, BS3, BS4, BS5, BS6, BS7, BS8);

    // wave (64-lane) reduction
    for (int off = 32; off > 0; off >>= 1) {
        local_sum += __shfl_down(local_sum, off, 64);
        local_max = fmaxf(local_max, __shfl_down(local_max, off, 64));
    }

    __shared__ double ssum[4];
    __shared__ float  smax[4];
    int wave = threadIdx.x >> 6;
    int lane = threadIdx.x & 63;
    if (lane == 0) { ssum[wave] = local_sum; smax[wave] = local_max; }
    __syncthreads();

    if (threadIdx.x == 0) {
        part_sum[blockIdx.x] = ssum[0] + ssum[1] + ssum[2] + ssum[3];
        part_max[blockIdx.x] = fmaxf(fmaxf(smax[0], smax[1]), fmaxf(smax[2], smax[3]));
    }
}

__global__ __launch_bounds__(256) void map_loss_finalize(
    const double* __restrict__ part_sum,
    const float* __restrict__ part_max,
    float* __restrict__ out)
{
    double s = 0.0;
    float m = 0.0f;
    for (int i = threadIdx.x; i < NBLK; i += 256) {
        s += part_sum[i];
        m = fmaxf(m, part_max[i]);
    }

    for (int off = 32; off > 0; off >>= 1) {
        s += __shfl_down(s, off, 64);
        m = fmaxf(m, __shfl_down(m, off, 64));
    }

    __shared__ double ssum[4];
    __shared__ float  smax[4];
    int wave = threadIdx.x >> 6;
    int lane = threadIdx.x & 63;
    if (lane == 0) { ssum[wave] = s; smax[wave] = m; }
    __syncthreads();

    if (threadIdx.x == 0) {
        double bs = ssum[0] + ssum[1] + ssum[2] + ssum[3];
        float  bm = fmaxf(fmaxf(smax[0], smax[1]), fmaxf(smax[2], smax[3]));
        out[0] = (bm > 1e8f) ? 0.0f : (float)(bs / (double)NPIX);
    }
}

extern "C" void kernel_launch(void* const* d_in, const int* in_sizes, int n_in,
                              void* d_out, int out_size, void* d_ws, size_t ws_size,
                              hipStream_t stream) {
    const float* target  = (const float*)d_in[0];
    const float* mu      = (const float*)d_in[1];
    // d_in[2] = sigma_mu (unused), d_in[3] = sigma_n (unused)
    const float* sigma_y = (const float*)d_in[4];
    float* out = (float*)d_out;

    double* part_sum = (double*)d_ws;
    float*  part_max = (float*)((char*)d_ws + NBLK * sizeof(double));
    // every slot is written unconditionally by its block — no pre-zeroing needed

    map_loss_main<<<NBLK, TPB, 0, stream>>>(target, mu, sigma_y, part_sum, part_max);
    map_loss_finalize<<<1, 256, 0, stream>>>(part_sum, part_max, out);
}

// Round 2
// 215.350 us; speedup vs baseline: 1.0137x; 1.0070x over previous
//
#include <hip/hip_runtime.h>

// Problem constants (from reference): B=8, C=3, H=512, W=512
constexpr int Cc = 3;
constexpr int Hc = 512;
constexpr int Wc = 512;
constexpr int HW = Hc * Wc;              // 262144 = 2^18
constexpr int NPIX = 8 * HW;             // 2097152
constexpr int TPB  = 256;
constexpr int PPT  = 4;                  // pixels per thread
constexpr int PPB  = TPB * PPT;          // 1024 pixels per block
constexpr int NBLK = NPIX / PPB;         // 2048 blocks
constexpr int SIG4_PER_BLK = PPB * 9 / 4;  // 2304 float4 (36 KB) of sigma per block

// ws layout: [0, NBLK) doubles = per-block partial sums
//            then NBLK floats = per-block partial maxes

__global__ __launch_bounds__(256, 4) void map_loss_main(
    const float* __restrict__ target,
    const float* __restrict__ mu,
    const float* __restrict__ sigma_y,
    double* __restrict__ part_sum,
    float* __restrict__ part_max)
{
    // 36 KB sigma staging buffer; swizzled layout: lds4[s] holds global f4 (s ^ ((s>>6)&7))
    __shared__ float4 lds4[SIG4_PER_BLK];

    const int tid = threadIdx.x;
    const int bid = blockIdx.x;

    // ---- per-thread residual loads (already per-instruction coalesced) ----
    const int g = bid * TPB + tid;           // 4-pixel group index
    const long long p0 = (long long)g << 2;
    const int b  = (int)(p0 >> 18);
    const int hw = (int)p0 & (HW - 1);
    const long long base = (long long)b * (Cc * HW) + hw;

    const float4* tg = (const float4*)(target + base);
    const float4* mm = (const float4*)(mu + base);
    float4 d0 = tg[0];        float4 m0 = mm[0];
    float4 d1 = tg[HW / 4];   float4 m1 = mm[HW / 4];
    float4 d2 = tg[HW / 2];   float4 m2 = mm[HW / 2];

    // ---- cooperative sigma staging: block slab = float4 [bid*2304, +2304) ----
    // Write side: linear LDS dest (global_load_lds requirement), source index
    // pre-swizzled by s ^ ((s>>6)&7).  The XOR term is wave-uniform per
    // instruction (s>>6 = 4j + waveid), so each wave-instruction still reads a
    // contiguous, permuted-within-1KB block: fully coalesced.
    const float4* sblk = (const float4*)sigma_y + (long long)bid * SIG4_PER_BLK;
    const int w = tid >> 6;
    #pragma unroll
    for (int j = 0; j < 9; ++j) {
        const int s = j * TPB + tid;         // linear dest slot
        const int c = (s >> 6) & 7;          // wave-uniform swizzle term
        __builtin_amdgcn_global_load_lds(
            (const __attribute__((address_space(1))) void*)(sblk + (s ^ c)),
            (__attribute__((address_space(3))) void*)(&lds4[j * TPB + w * 64]),
            16, 0, 0);
    }
    __syncthreads();                         // drains vmcnt (also covers tg/mm loads)

    // residuals
    d0.x -= m0.x; d0.y -= m0.y; d0.z -= m0.z; d0.w -= m0.w;
    d1.x -= m1.x; d1.y -= m1.y; d1.z -= m1.z; d1.w -= m1.w;
    d2.x -= m2.x; d2.y -= m2.y; d2.z -= m2.z; d2.w -= m2.w;

    // ---- swizzled LDS read: thread t's 144 B = slots 9t..9t+8 ----
    // read addr x = r ^ ((r>>6)&7): within any 8-lane phase, r spans <128 so
    // the XOR term takes <=2 values -> at most 2-way conflicts (free).
    union { float4 v[9]; float f[36]; } S;
    #pragma unroll
    for (int k = 0; k < 9; ++k) {
        const int r = 9 * tid + k;
        const int x = r ^ ((r >> 6) & 7);
        S.v[k] = lds4[x];
    }

    double local_sum = 0.0;
    float local_max = 0.0f;

    const float T0[4] = {d0.x, d0.y, d0.z, d0.w};
    const float T1[4] = {d1.x, d1.y, d1.z, d1.w};
    const float T2[4] = {d2.x, d2.y, d2.z, d2.w};

    #pragma unroll
    for (int i = 0; i < 4; ++i) {
        const float* s = S.f + i * 9;
        float s00 = s[0], s01 = s[1], s02 = s[2];
        float s11 = s[4], s12 = s[5], s22 = s[8];

        // adjugate (symmetric)
        float a00 = s11 * s22 - s12 * s12;
        float a01 = s02 * s12 - s01 * s22;
        float a02 = s01 * s12 - s02 * s11;
        float a11 = s00 * s22 - s02 * s02;
        float a12 = s01 * s02 - s00 * s12;
        float a22 = s00 * s11 - s01 * s01;

        float det = s00 * a00 + s01 * a01 + s02 * a02;

        float t0 = T0[i], t1 = T1[i], t2 = T2[i];
        float quad = t0 * t0 * a00 + t1 * t1 * a11 + t2 * t2 * a22
                   + 2.0f * (t0 * t1 * a01 + t0 * t2 * a02 + t1 * t2 * a12);

        float t1term = 0.5f * quad / det;
        float t2term = 0.5f * logf(det);

        local_sum += (double)(t1term + t2term);
        local_max = fmaxf(local_max, t1term);
    }

    // wave (64-lane) reduction
    for (int off = 32; off > 0; off >>= 1) {
        local_sum += __shfl_down(local_sum, off, 64);
        local_max = fmaxf(local_max, __shfl_down(local_max, off, 64));
    }

    __shared__ double ssum[4];
    __shared__ float  smax[4];
    int lane = threadIdx.x & 63;
    if (lane == 0) { ssum[w] = local_sum; smax[w] = local_max; }
    __syncthreads();

    if (threadIdx.x == 0) {
        part_sum[blockIdx.x] = ssum[0] + ssum[1] + ssum[2] + ssum[3];
        part_max[blockIdx.x] = fmaxf(fmaxf(smax[0], smax[1]), fmaxf(smax[2], smax[3]));
    }
}

__global__ __launch_bounds__(256) void map_loss_finalize(
    const double* __restrict__ part_sum,
    const float* __restrict__ part_max,
    float* __restrict__ out)
{
    double s = 0.0;
    float m = 0.0f;
    for (int i = threadIdx.x; i < NBLK; i += 256) {
        s += part_sum[i];
        m = fmaxf(m, part_max[i]);
    }

    for (int off = 32; off > 0; off >>= 1) {
        s += __shfl_down(s, off, 64);
        m = fmaxf(m, __shfl_down(m, off, 64));
    }

    __shared__ double ssum[4];
    __shared__ float  smax[4];
    int wave = threadIdx.x >> 6;
    int lane = threadIdx.x & 63;
    if (lane == 0) { ssum[wave] = s; smax[wave] = m; }
    __syncthreads();

    if (threadIdx.x == 0) {
        double bs = ssum[0] + ssum[1] + ssum[2] + ssum[3];
        float  bm = fmaxf(fmaxf(smax[0], smax[1]), fmaxf(smax[2], smax[3]));
        out[0] = (bm > 1e8f) ? 0.0f : (float)(bs / (double)NPIX);
    }
}

extern "C" void kernel_launch(void* const* d_in, const int* in_sizes, int n_in,
                              void* d_out, int out_size, void* d_ws, size_t ws_size,
                              hipStream_t stream) {
    const float* target  = (const float*)d_in[0];
    const float* mu      = (const float*)d_in[1];
    // d_in[2] = sigma_mu (unused), d_in[3] = sigma_n (unused)
    const float* sigma_y = (const float*)d_in[4];
    float* out = (float*)d_out;

    double* part_sum = (double*)d_ws;
    float*  part_max = (float*)((char*)d_ws + NBLK * sizeof(double));
    // every slot is written unconditionally by its block — no pre-zeroing needed

    map_loss_main<<<NBLK, TPB, 0, stream>>>(target, mu, sigma_y, part_sum, part_max);
    map_loss_finalize<<<1, 256, 0, stream>>>(part_sum, part_max, out);
}